// Round 1
// baseline (356.151 us; speedup 1.0000x reference)
//
#include <hip/hip_runtime.h>

#define NPIX (512 * 512)
#define IMW 512
#define IMH 512

// ---------------------------------------------------------------------------
// Kernel 1: fused pointwise transforms, thread-per-pixel.
//   proj_t  [N][64]  pixel-major 1x1-conv output (so gathers are contiguous)
//   flows_t [N][8]   (k0x,k0y,k1x,k1y,k2x,k2y,k3x,k3y)
//   wts_t   [N][4]   softmax'd blend weights
// Weight matrices are wave-uniform loads -> scalar (s_load) path; input loads
// are fully coalesced (lane i -> pixel n0+i).
// ---------------------------------------------------------------------------
__global__ __launch_bounds__(256) void k1_pointwise(
    const float* __restrict__ in, const float* __restrict__ conv_w,
    const float* __restrict__ conv_b, const float* __restrict__ offset_w,
    const float* __restrict__ offset_b, const float* __restrict__ wconv_w,
    const float* __restrict__ wconv_b, float* __restrict__ proj_t,
    float* __restrict__ flows_t, float* __restrict__ wts_t) {
  const int n = blockIdx.x * 256 + threadIdx.x;

  float acc[64];
#pragma unroll
  for (int o = 0; o < 64; ++o) acc[o] = conv_b[o];
  float fac[8];
#pragma unroll
  for (int f = 0; f < 8; ++f) fac[f] = offset_b[f];
  float wac[4];
#pragma unroll
  for (int k = 0; k < 4; ++k) wac[k] = wconv_b[k];

  // K-loop over input channels, 8 at a time. Keep outer loop rolled so the
  // ~5KB body stays in I$; inner loops fully unrolled so acc[] stays in VGPRs.
#pragma unroll 1
  for (int cb = 0; cb < 64; cb += 8) {
    float x[8];
#pragma unroll
    for (int j = 0; j < 8; ++j) x[j] = in[(size_t)(cb + j) * NPIX + n];
#pragma unroll
    for (int o = 0; o < 64; ++o) {
#pragma unroll
      for (int j = 0; j < 8; ++j)
        acc[o] = fmaf(x[j], conv_w[o * 64 + cb + j], acc[o]);
    }
#pragma unroll
    for (int f = 0; f < 8; ++f) {
#pragma unroll
      for (int j = 0; j < 8; ++j)
        fac[f] = fmaf(x[j], offset_w[f * 64 + cb + j], fac[f]);
    }
#pragma unroll
    for (int k = 0; k < 4; ++k) {
#pragma unroll
      for (int j = 0; j < 8; ++j)
        wac[k] = fmaf(x[j], wconv_w[k * 64 + cb + j], wac[k]);
    }
  }

  // softmax over K=4
  const float m = fmaxf(fmaxf(wac[0], wac[1]), fmaxf(wac[2], wac[3]));
  const float e0 = __expf(wac[0] - m), e1 = __expf(wac[1] - m);
  const float e2 = __expf(wac[2] - m), e3 = __expf(wac[3] - m);
  const float inv = 1.f / (e0 + e1 + e2 + e3);
  *(float4*)(wts_t + (size_t)n * 4) =
      make_float4(e0 * inv, e1 * inv, e2 * inv, e3 * inv);

  float4* fl4 = (float4*)(flows_t + (size_t)n * 8);
  fl4[0] = make_float4(fac[0], fac[1], fac[2], fac[3]);
  fl4[1] = make_float4(fac[4], fac[5], fac[6], fac[7]);

  float4* pj = (float4*)(proj_t + (size_t)n * 64);
#pragma unroll
  for (int q = 0; q < 16; ++q)
    pj[q] = make_float4(acc[4 * q + 0], acc[4 * q + 1], acc[4 * q + 2],
                        acc[4 * q + 3]);
}

// ---------------------------------------------------------------------------
// Kernel 2: deformable bilinear gather + K-blend.
// 16-lane group per pixel (lane l -> channels 4l..4l+3), 4 px per wave,
// 64 px per 256-thread block. Results staged in LDS then transpose-written
// so each channel's store is a 256B contiguous run (output is [C,H,W]).
// ---------------------------------------------------------------------------
__global__ __launch_bounds__(256) void k2_sample(
    const float* __restrict__ ax, const float* __restrict__ ay,
    const float* __restrict__ proj_t, const float* __restrict__ flows_t,
    const float* __restrict__ wts_t, float* __restrict__ out) {
  __shared__ float tile[64][68];  // [px][ch], +4 pad to break bank alignment
  const int t = threadIdx.x;
  const int g = t >> 4;   // pixel-group within block-pass
  const int l = t & 15;   // lane within group: channels 4l..4l+3
  const int p0 = blockIdx.x * 64;

#pragma unroll 1
  for (int pass = 0; pass < 4; ++pass) {
    const int pl = pass * 16 + g;
    const int p = p0 + pl;
    const float axv = ax[p];
    const float ayv = ay[p];
    const int ixi = (int)axv;  // trunc; ax,ay >= 0
    const int iyi = (int)ayv;
    const size_t n2 = (size_t)(iyi * IMW + ixi);
    const float4 f01 = *(const float4*)(flows_t + n2 * 8);
    const float4 f23 = *(const float4*)(flows_t + n2 * 8 + 4);
    const float4 wk4 = *(const float4*)(wts_t + (size_t)p * 4);
    const float fx[4] = {f01.x, f01.z, f23.x, f23.z};
    const float fy[4] = {f01.y, f01.w, f23.y, f23.w};
    const float wk[4] = {wk4.x, wk4.y, wk4.z, wk4.w};

    float4 acc = make_float4(0.f, 0.f, 0.f, 0.f);
#pragma unroll
    for (int k = 0; k < 4; ++k) {
      const float xs = (axv + fx[k]) * (512.f / 511.f) - 0.5f;
      const float ys = (ayv + fy[k]) * (512.f / 511.f) - 0.5f;
      const float x0f = floorf(xs), y0f = floorf(ys);
      const float wx = xs - x0f, wy = ys - y0f;
      const int x0 = (int)x0f, y0 = (int)y0f;
      const int x1 = x0 + 1, y1 = y0 + 1;
      const int cx0 = min(max(x0, 0), IMW - 1);
      const int cx1 = min(max(x1, 0), IMW - 1);
      const int cy0 = min(max(y0, 0), IMH - 1);
      const int cy1 = min(max(y1, 0), IMH - 1);
      const float vx0 = (x0 >= 0 && x0 < IMW) ? 1.f : 0.f;
      const float vx1 = (x1 >= 0 && x1 < IMW) ? 1.f : 0.f;
      const float vy0 = (y0 >= 0 && y0 < IMH) ? 1.f : 0.f;
      const float vy1 = (y1 >= 0 && y1 < IMH) ? 1.f : 0.f;
      const float s00 = wk[k] * (1.f - wx) * (1.f - wy) * vx0 * vy0;
      const float s10 = wk[k] * wx * (1.f - wy) * vx1 * vy0;
      const float s01 = wk[k] * (1.f - wx) * wy * vx0 * vy1;
      const float s11 = wk[k] * wx * wy * vx1 * vy1;

      const float4 v00 =
          *(const float4*)(proj_t + (size_t)(cy0 * IMW + cx0) * 64 + l * 4);
      const float4 v10 =
          *(const float4*)(proj_t + (size_t)(cy0 * IMW + cx1) * 64 + l * 4);
      const float4 v01 =
          *(const float4*)(proj_t + (size_t)(cy1 * IMW + cx0) * 64 + l * 4);
      const float4 v11 =
          *(const float4*)(proj_t + (size_t)(cy1 * IMW + cx1) * 64 + l * 4);

      acc.x += s00 * v00.x + s10 * v10.x + s01 * v01.x + s11 * v11.x;
      acc.y += s00 * v00.y + s10 * v10.y + s01 * v01.y + s11 * v11.y;
      acc.z += s00 * v00.z + s10 * v10.z + s01 * v01.z + s11 * v11.z;
      acc.w += s00 * v00.w + s10 * v10.w + s01 * v01.w + s11 * v11.w;
    }
    *(float4*)&tile[pl][4 * l] = acc;
  }
  __syncthreads();

  // Transpose-store: iter covers 16 channels x 16 pixel-quads.
#pragma unroll
  for (int it = 0; it < 4; ++it) {
    const int c = it * 16 + g;
    float4 vv;
    vv.x = tile[4 * l + 0][c];
    vv.y = tile[4 * l + 1][c];
    vv.z = tile[4 * l + 2][c];
    vv.w = tile[4 * l + 3][c];
    *(float4*)(out + (size_t)c * NPIX + p0 + 4 * l) = vv;
  }
}

extern "C" void kernel_launch(void* const* d_in, const int* in_sizes, int n_in,
                              void* d_out, int out_size, void* d_ws,
                              size_t ws_size, hipStream_t stream) {
  const float* input = (const float*)d_in[0];
  const float* ax = (const float*)d_in[1];
  const float* ay = (const float*)d_in[2];
  const float* conv_w = (const float*)d_in[3];
  const float* conv_b = (const float*)d_in[4];
  const float* offset_w = (const float*)d_in[5];
  const float* offset_b = (const float*)d_in[6];
  const float* wconv_w = (const float*)d_in[7];
  const float* wconv_b = (const float*)d_in[8];
  float* out = (float*)d_out;

  float* proj_t = (float*)d_ws;                   // 64 MiB
  float* flows_t = proj_t + (size_t)NPIX * 64;    // 8 MiB
  float* wts_t = flows_t + (size_t)NPIX * 8;      // 4 MiB

  hipLaunchKernelGGL(k1_pointwise, dim3(NPIX / 256), dim3(256), 0, stream,
                     input, conv_w, conv_b, offset_w, offset_b, wconv_w,
                     wconv_b, proj_t, flows_t, wts_t);
  hipLaunchKernelGGL(k2_sample, dim3(NPIX / 64), dim3(256), 0, stream, ax, ay,
                     proj_t, flows_t, wts_t, out);
}